// Round 10
// baseline (173.580 us; speedup 1.0000x reference)
//
#include <hip/hip_runtime.h>
#include <math.h>

constexpr int B_  = 2;
constexpr int N_  = 10000;
constexpr int E_  = 160000;
constexpr int H_  = 128;
constexpr int ET_ = 8;
constexpr int CAP_ = 64;               // slots per tgt node; P(deg>=64) ~ 2e-18
constexpr float EPS_ = 1e-5f;
constexpr float RSQH = 0.08838834764831845f; // 1/sqrt(128)
constexpr int NSTRIDE = 384;           // bytes per node: K bf16 (256) | V fp8 (128)

typedef __bf16 bf16x8 __attribute__((ext_vector_type(8)));
typedef short  short8 __attribute__((ext_vector_type(8)));
typedef float  f32x4  __attribute__((ext_vector_type(4)));
typedef float  f32x2  __attribute__((ext_vector_type(2)));
typedef unsigned short u16;
typedef unsigned char  u8;

__device__ inline u16 bf16b(float f) {
    return __builtin_bit_cast(u16, (__bf16)f);
}

// OCP e4m3 encode (low byte of packed pair)
__device__ inline u8 fp8b(float f) {
    int v = __builtin_amdgcn_cvt_pk_fp8_f32(f, 0.f, 0, false);
    return (u8)(v & 0xFF);
}

// 8 OCP e4m3 bytes -> 8 floats
__device__ inline void cvt8(uint2 u, float* f) {
    f32x2 a = __builtin_amdgcn_cvt_pk_f32_fp8(u.x, false);
    f32x2 b = __builtin_amdgcn_cvt_pk_f32_fp8(u.x, true);
    f32x2 c = __builtin_amdgcn_cvt_pk_f32_fp8(u.y, false);
    f32x2 d = __builtin_amdgcn_cvt_pk_f32_fp8(u.y, true);
    f[0]=a[0]; f[1]=a[1]; f[2]=b[0]; f[3]=b[1];
    f[4]=c[0]; f[5]=c[1]; f[6]=d[0]; f[7]=d[1];
}

__device__ inline bf16x8 ldfrag(const u16* __restrict__ W, int kc, int nt, int lane) {
    short8 s = *(const short8*)(W + ((kc * 8 + nt) * 64 + lane) * 8);
    return __builtin_bit_cast(bf16x8, s);
}

// ---------------------------------------------------------------------------
// Setup: blocks [0,56) weight-prep, [56,64) edge-type tables,
// [64,74) zero count[].  (unchanged)
// ---------------------------------------------------------------------------
__global__ __launch_bounds__(256)
void setup_kernel(const float* __restrict__ W1, const float* __restrict__ W2,
                  const float* __restrict__ Wq, const float* __restrict__ Wk,
                  const float* __restrict__ Wv,
                  u16* __restrict__ W1s, u16* __restrict__ W2s,
                  u16* __restrict__ Wqs, u16* __restrict__ Wks, u16* __restrict__ Wvs,
                  const float* __restrict__ edge_emb,
                  const float* __restrict__ bk, const float* __restrict__ bv,
                  const float* __restrict__ We, const float* __restrict__ be,
                  float* __restrict__ Kt, float* __restrict__ Vt, float* __restrict__ eb,
                  int* __restrict__ count)
{
    const int bid = blockIdx.x, tid = threadIdx.x;
    if (bid < 56) {
        int unit = bid >> 1, half = bid & 1;
        const float* src; u16* dst; int kc;
        if (unit < 12)      { src = W1; dst = W1s; kc = unit; }
        else if (unit < 16) { src = W2; dst = W2s; kc = unit - 12; }
        else if (unit < 20) { src = Wq; dst = Wqs; kc = unit - 16; }
        else if (unit < 24) { src = Wk; dst = Wks; kc = unit - 20; }
        else                { src = Wv; dst = Wvs; kc = unit - 24; }
        int nt = half * 4 + (tid >> 6), lane = tid & 63;
        int q = lane >> 4, c = lane & 15;
        int kbase = kc * 32 + q * 8;
        int col = nt * 16 + c;
        u16* out = dst + ((kc * 8 + nt) * 64 + lane) * 8;
#pragma unroll
        for (int j = 0; j < 8; ++j)
            out[j] = bf16b(src[(kbase + j) * H_ + col]);
    } else if (bid < 64) {
        int t = bid - 56;
        const float* ep = edge_emb + t * H_;
        __shared__ float red[2];
        int j = tid;
        if (j < 128) {
            float ak = bk[j], av = bv[j];
            for (int d = 0; d < H_; d += 4) {
                float e0 = ep[d], e1 = ep[d+1], e2 = ep[d+2], e3 = ep[d+3];
                ak += e0*Wk[(d+0)*H_+j] + e1*Wk[(d+1)*H_+j] + e2*Wk[(d+2)*H_+j] + e3*Wk[(d+3)*H_+j];
                av += e0*Wv[(d+0)*H_+j] + e1*Wv[(d+1)*H_+j] + e2*Wv[(d+2)*H_+j] + e3*Wv[(d+3)*H_+j];
            }
            Kt[t*H_ + j] = ak;
            Vt[t*H_ + j] = av;
            float pe = ep[j] * We[j];
#pragma unroll
            for (int off = 32; off; off >>= 1) pe += __shfl_xor(pe, off);
            if ((j & 63) == 0) red[j >> 6] = pe;
        }
        __syncthreads();
        if (j == 0) eb[t] = red[0] + red[1] + be[0];
    } else {
        int i0 = (bid - 64) * 1024;
        for (int i = i0 + tid; i < i0 + 1024; i += 256)
            if (i < N_) count[i] = 0;
    }
}

// ---------------------------------------------------------------------------
// Fused scatter (blocks [0,625)) + Q/KV MFMA (blocks [625,938)).
// Per-node record (384 B): K bf16 at bytes [0,256), V fp8 e4m3 at [256,384).
// K stays bf16 (softmax amplifies K-quant error exponentially); V fp8 is the
// numerically-benign linear term.  Q stays bf16.
// ---------------------------------------------------------------------------
__global__ __launch_bounds__(256)
void scatter_qkv_kernel(const int* __restrict__ src, const int* __restrict__ tgt,
                        const int* __restrict__ type, int* __restrict__ count,
                        int* __restrict__ slots,
                        const float* __restrict__ hidden, const float* __restrict__ time_emb,
                        const u16* __restrict__ Wqs, const u16* __restrict__ Wks,
                        const u16* __restrict__ Wvs, const float* __restrict__ bq,
                        u16* __restrict__ Q, u8* __restrict__ KV)
{
    if (blockIdx.x < 625) {
        int e = blockIdx.x * 256 + threadIdx.x;
        if (e < E_) {
            int t = tgt[e];
            int pos = atomicAdd(&count[t], 1);
            slots[t * CAP_ + pos] = src[e] | (type[e] << 16);
        }
        return;
    }
    const int wv = threadIdx.x >> 6, lane = threadIdx.x & 63;
    const int tile = (blockIdx.x - 625) * 4 + wv;
    if (tile >= (B_ * N_) / 16) return;
    const int nbase = tile * 16;
    const int m = lane & 15, q = lane >> 4;
    const int koff = q * 8;

    bf16x8 aq[4], av[4];
    const float* hp = hidden   + (nbase + m) * H_ + koff;
    const float* tp = time_emb + (nbase + m) * H_ + koff;
#pragma unroll
    for (int kc = 0; kc < 4; ++kc) {
        float4 h0 = *(const float4*)(hp + kc * 32);
        float4 h1 = *(const float4*)(hp + kc * 32 + 4);
        float4 t0 = *(const float4*)(tp + kc * 32);
        float4 t1 = *(const float4*)(tp + kc * 32 + 4);
        bf16x8 fv, fq;
        fv[0]=(__bf16)h0.x; fv[1]=(__bf16)h0.y; fv[2]=(__bf16)h0.z; fv[3]=(__bf16)h0.w;
        fv[4]=(__bf16)h1.x; fv[5]=(__bf16)h1.y; fv[6]=(__bf16)h1.z; fv[7]=(__bf16)h1.w;
        fq[0]=(__bf16)(h0.x+t0.x); fq[1]=(__bf16)(h0.y+t0.y);
        fq[2]=(__bf16)(h0.z+t0.z); fq[3]=(__bf16)(h0.w+t0.w);
        fq[4]=(__bf16)(h1.x+t1.x); fq[5]=(__bf16)(h1.y+t1.y);
        fq[6]=(__bf16)(h1.z+t1.z); fq[7]=(__bf16)(h1.w+t1.w);
        av[kc] = fv; aq[kc] = fq;
    }

    f32x4 accq[8], acck[8], accv[8];
#pragma unroll
    for (int nt = 0; nt < 8; ++nt) { accq[nt] = (f32x4)0.f; acck[nt] = (f32x4)0.f; accv[nt] = (f32x4)0.f; }

#pragma unroll
    for (int kc = 0; kc < 4; ++kc) {
#pragma unroll
        for (int nt = 0; nt < 8; ++nt) {
            bf16x8 bfq = ldfrag(Wqs, kc, nt, lane);
            bf16x8 bfk = ldfrag(Wks, kc, nt, lane);
            bf16x8 bfv = ldfrag(Wvs, kc, nt, lane);
            accq[nt] = __builtin_amdgcn_mfma_f32_16x16x32_bf16(aq[kc], bfq, accq[nt], 0, 0, 0);
            acck[nt] = __builtin_amdgcn_mfma_f32_16x16x32_bf16(aq[kc], bfk, acck[nt], 0, 0, 0);
            accv[nt] = __builtin_amdgcn_mfma_f32_16x16x32_bf16(av[kc], bfv, accv[nt], 0, 0, 0);
        }
    }

#pragma unroll
    for (int nt = 0; nt < 8; ++nt) {
        int col = nt * 16 + m;
        float bqc = bq[col];
#pragma unroll
        for (int r = 0; r < 4; ++r) {
            int node = nbase + q * 4 + r;
            Q[(size_t)node * H_ + col] = bf16b(accq[nt][r] + bqc);
            u16* krow = (u16*)(KV + (size_t)node * NSTRIDE);
            krow[col] = bf16b(acck[nt][r]);
            KV[(size_t)node * NSTRIDE + 256 + col] = fp8b(accv[nt][r]);
        }
    }
}

// ---------------------------------------------------------------------------
// Attention: one wave per (b,node); groups of 16 lanes; single-pass online
// softmax, deferred rescale (THR=8); 2 edges in flight; slot list preloaded
// to registers.  Per-edge gather: one 384-B record (K bf16 + V fp8);
// 3.84 MB/batch working set -> L2-resident per XCD.
// ---------------------------------------------------------------------------
__global__ __launch_bounds__(256)
void attn_kernel(const u16* __restrict__ Qb, const u8* __restrict__ KV,
                 const float* __restrict__ Kt, const float* __restrict__ Vt,
                 const float* __restrict__ eb,
                 const int* __restrict__ count, const int* __restrict__ slots,
                 u16* __restrict__ aggb)
{
    __shared__ float bias_s[4][8];
    __shared__ __align__(16) u16 vt_s[8][128];

    const int tid = threadIdx.x;
    const int wv = tid >> 6, lane = tid & 63;
    const int g = lane >> 4, lam = lane & 15;

    for (int idx = tid; idx < ET_ * H_; idx += 256)
        vt_s[idx >> 7][idx & 127] = bf16b(Vt[idx]);
    __syncthreads();

    const int b = (blockIdx.x >= (N_ / 4)) ? 1 : 0;   // batch-contiguous halves
    const int n = (blockIdx.x - b * (N_ / 4)) * 4 + wv;
    const int bn = b * N_ + n;
    const int cnt = count[n];
    const int sbase = n * CAP_;
    const u8* __restrict__ KVb = KV + (size_t)(b * N_) * NSTRIDE;

    // preload slot list: lane lam of group g holds edge g + 4*lam
    int myslot = 0;
    {
        int idx = g + 4 * lam;
        if (idx < cnt) myslot = slots[sbase + idx];
    }
    const int lb = lane & 48;    // group base lane

    float q[8];
    {
        short8 s8 = *(const short8*)(Qb + (size_t)bn * H_ + lam * 8);
        bf16x8 qa = __builtin_bit_cast(bf16x8, s8);
#pragma unroll
        for (int j = 0; j < 8; ++j) q[j] = (float)qa[j];
    }

    {   // per-type logit bias: group g computes types 2g, 2g+1
        const float* k0p = Kt + (2 * g) * H_ + lam * 8;
        const float* k1p = Kt + (2 * g + 1) * H_ + lam * 8;
        float p0 = 0.f, p1 = 0.f;
#pragma unroll
        for (int j = 0; j < 8; ++j) { p0 += q[j] * k0p[j]; p1 += q[j] * k1p[j]; }
#pragma unroll
        for (int msk = 1; msk < 16; msk <<= 1) {
            p0 += __shfl_xor(p0, msk);
            p1 += __shfl_xor(p1, msk);
        }
        if (lam == 0) {
            bias_s[wv][2 * g]     = p0 * RSQH + eb[2 * g];
            bias_s[wv][2 * g + 1] = p1 * RSQH + eb[2 * g + 1];
        }
    }
    // bias_s row written/read by the same wave -> wave-synchronous

    float m_g = -INFINITY, l_g = 0.f;
    float acc[8];
#pragma unroll
    for (int j = 0; j < 8; ++j) acc[j] = 0.f;

    int c = g;
    for (; c + 4 < cnt; c += 8) {
        int r = (c - g) >> 2;                 // 0,2,4,...
        int pk0 = __shfl(myslot, lb + r);
        int pk1 = __shfl(myslot, lb + r + 1);
        int s0 = pk0 & 0xFFFF, t0 = pk0 >> 16;
        int s1 = pk1 & 0xFFFF, t1 = pk1 >> 16;
        const u8* base0 = KVb + (size_t)s0 * NSTRIDE;
        const u8* base1 = KVb + (size_t)s1 * NSTRIDE;
        // co-issue K (bf16) and V (fp8) for both edges — one 384-B region each
        short8 k80 = *(const short8*)(base0 + lam * 16);
        short8 k81 = *(const short8*)(base1 + lam * 16);
        uint2  v80 = *(const uint2*)(base0 + 256 + lam * 8);
        uint2  v81 = *(const uint2*)(base1 + 256 + lam * 8);
        short8 vt80 = *(const short8*)(&vt_s[t0][lam * 8]);
        short8 vt81 = *(const short8*)(&vt_s[t1][lam * 8]);
        bf16x8 ka0 = __builtin_bit_cast(bf16x8, k80);
        bf16x8 ka1 = __builtin_bit_cast(bf16x8, k81);
        float p0 = 0.f, p1 = 0.f;
#pragma unroll
        for (int j = 0; j < 8; ++j) {
            p0 += q[j] * (float)ka0[j];
            p1 += q[j] * (float)ka1[j];
        }
#pragma unroll
        for (int msk = 1; msk < 16; msk <<= 1) {
            p0 += __shfl_xor(p0, msk);
            p1 += __shfl_xor(p1, msk);
        }
        float lg0 = p0 * RSQH + bias_s[wv][t0];
        float lg1 = p1 * RSQH + bias_s[wv][t1];
        float mx = fmaxf(lg0, lg1);
        if (mx > m_g + 8.f) {          // deferred rescale (T13)
            float rs = __expf(m_g - mx);   // first trigger: exp(-inf)=0
            l_g *= rs;
#pragma unroll
            for (int j = 0; j < 8; ++j) acc[j] *= rs;
            m_g = mx;
        }
        float w0 = __expf(lg0 - m_g);
        float w1 = __expf(lg1 - m_g);
        l_g += w0 + w1;
        float vf0[8], vf1[8];
        cvt8(v80, vf0);
        cvt8(v81, vf1);
        bf16x8 vta0 = __builtin_bit_cast(bf16x8, vt80);
        bf16x8 vta1 = __builtin_bit_cast(bf16x8, vt81);
#pragma unroll
        for (int j = 0; j < 8; ++j)
            acc[j] += w0 * (vf0[j] + (float)vta0[j])
                    + w1 * (vf1[j] + (float)vta1[j]);
    }
    if (c < cnt) {
        int r = (c - g) >> 2;
        int pk0 = __shfl(myslot, lb + r);
        int s0 = pk0 & 0xFFFF, t0 = pk0 >> 16;
        const u8* base0 = KVb + (size_t)s0 * NSTRIDE;
        short8 k80 = *(const short8*)(base0 + lam * 16);
        uint2  v80 = *(const uint2*)(base0 + 256 + lam * 8);
        short8 vt80 = *(const short8*)(&vt_s[t0][lam * 8]);
        bf16x8 ka0 = __builtin_bit_cast(bf16x8, k80);
        float p0 = 0.f;
#pragma unroll
        for (int j = 0; j < 8; ++j) p0 += q[j] * (float)ka0[j];
#pragma unroll
        for (int msk = 1; msk < 16; msk <<= 1) p0 += __shfl_xor(p0, msk);
        float lg0 = p0 * RSQH + bias_s[wv][t0];
        if (lg0 > m_g + 8.f) {
            float rs = __expf(m_g - lg0);
            l_g *= rs;
#pragma unroll
            for (int j = 0; j < 8; ++j) acc[j] *= rs;
            m_g = lg0;
        }
        float w0 = __expf(lg0 - m_g);
        l_g += w0;
        float vf0[8];
        cvt8(v80, vf0);
        bf16x8 vta0 = __builtin_bit_cast(bf16x8, vt80);
#pragma unroll
        for (int j = 0; j < 8; ++j)
            acc[j] += w0 * (vf0[j] + (float)vta0[j]);
    }

    // merge the 4 groups (reconverged here): max + rescale + sum
    float M = fmaxf(m_g, __shfl_xor(m_g, 16));
    M = fmaxf(M, __shfl_xor(M, 32));
    float rs = (m_g == M) ? 1.f : __expf(m_g - M);  // guards -inf - -inf = NaN
    l_g *= rs;
#pragma unroll
    for (int j = 0; j < 8; ++j) {
        acc[j] *= rs;
        acc[j] += __shfl_xor(acc[j], 16);
        acc[j] += __shfl_xor(acc[j], 32);
    }
    l_g += __shfl_xor(l_g, 16);
    l_g += __shfl_xor(l_g, 32);

    if (g == 0) {
        float invL = (cnt > 0) ? 1.f / l_g : 0.f;
        bf16x8 o;
#pragma unroll
        for (int j = 0; j < 8; ++j) o[j] = (__bf16)(acc[j] * invL);
        *(short8*)(aggb + (size_t)bn * H_ + lam * 8) = __builtin_bit_cast(short8, o);
    }
}

// ---------------------------------------------------------------------------
// MLP + residual + LayerNorm via MFMA.  313 blocks x 4 waves.  Unchanged.
// ---------------------------------------------------------------------------
__global__ __launch_bounds__(256)
void mlp_mfma_kernel(const float* __restrict__ hidden, const u16* __restrict__ aggb,
                     const float* __restrict__ time_emb,
                     const u16* __restrict__ W1s, const u16* __restrict__ W2s,
                     const float* __restrict__ b1, const float* __restrict__ b2,
                     const float* __restrict__ gamma, const float* __restrict__ beta,
                     float* __restrict__ out)
{
    __shared__ __align__(16) u16 h1s[4][16][136];
    const int wv = threadIdx.x >> 6, lane = threadIdx.x & 63;
    const int tile = blockIdx.x * 4 + wv;
    if (tile >= (B_ * N_) / 16) return;
    const int nbase = tile * 16;
    const int m = lane & 15, q = lane >> 4;
    const int koff = q * 8;

    bf16x8 a[12];
    const float* hp = hidden   + (nbase + m) * H_ + koff;
    const float* tp = time_emb + (nbase + m) * H_ + koff;
    const u16*   ap = aggb + (size_t)(nbase + m) * H_ + koff;
#pragma unroll
    for (int kc = 0; kc < 4; ++kc) {
        float4 h0 = *(const float4*)(hp + kc * 32);
        float4 h1 = *(const float4*)(hp + kc * 32 + 4);
        float4 t0 = *(const float4*)(tp + kc * 32);
        float4 t1 = *(const float4*)(tp + kc * 32 + 4);
        bf16x8 fh, ft;
        fh[0]=(__bf16)h0.x; fh[1]=(__bf16)h0.y; fh[2]=(__bf16)h0.z; fh[3]=(__bf16)h0.w;
        fh[4]=(__bf16)h1.x; fh[5]=(__bf16)h1.y; fh[6]=(__bf16)h1.z; fh[7]=(__bf16)h1.w;
        ft[0]=(__bf16)t0.x; ft[1]=(__bf16)t0.y; ft[2]=(__bf16)t0.z; ft[3]=(__bf16)t0.w;
        ft[4]=(__bf16)t1.x; ft[5]=(__bf16)t1.y; ft[6]=(__bf16)t1.z; ft[7]=(__bf16)t1.w;
        a[0 * 4 + kc] = fh;
        a[2 * 4 + kc] = ft;
        short8 s8 = *(const short8*)(ap + kc * 32);
        a[1 * 4 + kc] = __builtin_bit_cast(bf16x8, s8);
    }

    f32x4 acc[8];
#pragma unroll
    for (int nt = 0; nt < 8; ++nt) acc[nt] = (f32x4)0.f;
#pragma unroll
    for (int kc = 0; kc < 12; ++kc) {
#pragma unroll
        for (int nt = 0; nt < 8; ++nt) {
            bf16x8 bf = ldfrag(W1s, kc, nt, lane);
            acc[nt] = __builtin_amdgcn_mfma_f32_16x16x32_bf16(a[kc], bf, acc[nt], 0, 0, 0);
        }
    }

#pragma unroll
    for (int nt = 0; nt < 8; ++nt) {
        int col = nt * 16 + m;
        float bb = b1[col];
#pragma unroll
        for (int r = 0; r < 4; ++r) {
            float v = acc[nt][r] + bb;
            float h = v / (1.f + __expf(-v));
            h1s[wv][q * 4 + r][col] = bf16b(h);
        }
    }

    f32x4 acc2[8];
#pragma unroll
    for (int nt = 0; nt < 8; ++nt) acc2[nt] = (f32x4)0.f;
#pragma unroll
    for (int kc = 0; kc < 4; ++kc) {
        short8 s8 = *(const short8*)&h1s[wv][m][kc * 32 + koff];
        bf16x8 a2 = __builtin_bit_cast(bf16x8, s8);
#pragma unroll
        for (int nt = 0; nt < 8; ++nt) {
            bf16x8 bf = ldfrag(W2s, kc, nt, lane);
            acc2[nt] = __builtin_amdgcn_mfma_f32_16x16x32_bf16(a2, bf, acc2[nt], 0, 0, 0);
        }
    }

    float x[8][4];
#pragma unroll
    for (int nt = 0; nt < 8; ++nt) {
        int col = nt * 16 + m;
        float bb = b2[col];
#pragma unroll
        for (int r = 0; r < 4; ++r) {
            int node = nbase + q * 4 + r;
            x[nt][r] = hidden[node * H_ + col] + acc2[nt][r] + bb;
        }
    }
#pragma unroll
    for (int r = 0; r < 4; ++r) {
        float s = 0.f, ss = 0.f;
#pragma unroll
        for (int nt = 0; nt < 8; ++nt) { s += x[nt][r]; ss += x[nt][r] * x[nt][r]; }
#pragma unroll
        for (int off = 1; off < 16; off <<= 1) {
            s  += __shfl_xor(s, off);
            ss += __shfl_xor(ss, off);
        }
        float mu  = s * (1.f / H_);
        float var = ss * (1.f / H_) - mu * mu;
        float rs  = rsqrtf(var + EPS_);
        int node = nbase + q * 4 + r;
#pragma unroll
        for (int nt = 0; nt < 8; ++nt) {
            int col = nt * 16 + m;
            out[node * H_ + col] = (x[nt][r] - mu) * rs * gamma[col] + beta[col];
        }
    }
}

// ---------------------------------------------------------------------------
extern "C" void kernel_launch(void* const* d_in, const int* in_sizes, int n_in,
                              void* d_out, int out_size, void* d_ws, size_t ws_size,
                              hipStream_t stream)
{
    const float* hidden   = (const float*)d_in[0];
    const float* time_emb = (const float*)d_in[1];
    const int*   eidx     = (const int*)d_in[2];
    const int*   etype    = (const int*)d_in[3];
    const float* edge_emb = (const float*)d_in[4];
    const float* Wq = (const float*)d_in[5];
    const float* bq = (const float*)d_in[6];
    const float* Wk = (const float*)d_in[7];
    const float* bk = (const float*)d_in[8];
    const float* Wv = (const float*)d_in[9];
    const float* bv = (const float*)d_in[10];
    const float* We = (const float*)d_in[11];
    const float* be = (const float*)d_in[12];
    const float* W1 = (const float*)d_in[13];
    const float* b1 = (const float*)d_in[14];
    const float* W2 = (const float*)d_in[15];
    const float* b2 = (const float*)d_in[16];
    const float* gamma = (const float*)d_in[17];
    const float* beta  = (const float*)d_in[18];
    float* out = (float*)d_out;

    constexpr int BNH = B_ * N_ * H_;
    u16* Qb   = (u16*)d_ws;                        // B*N*128 bf16
    u8*  KVb  = (u8*)(Qb + BNH);                   // B*N*384 bytes (K bf16 | V fp8)
    u16* aggb = (u16*)(KVb + (size_t)B_ * N_ * NSTRIDE);
    float* Kt  = (float*)(aggb + BNH);
    float* Vt  = Kt + ET_ * H_;
    float* ebt = Vt + ET_ * H_;
    int* count = (int*)(ebt + ET_);
    int* slots = count + N_;                       // N*CAP ints
    uintptr_t wp = (uintptr_t)(slots + N_ * CAP_);
    wp = (wp + 15) & ~(uintptr_t)15;
    u16* W1s = (u16*)wp;
    u16* W2s = W1s + 384 * 128;
    u16* Wqs = W2s + 128 * 128;
    u16* Wks = Wqs + 128 * 128;
    u16* Wvs = Wks + 128 * 128;

    const int* esrc = eidx;
    const int* etgt = eidx + E_;

    setup_kernel<<<74, 256, 0, stream>>>(
        W1, W2, Wq, Wk, Wv, W1s, W2s, Wqs, Wks, Wvs,
        edge_emb, bk, bv, We, be, Kt, Vt, ebt, count);
    scatter_qkv_kernel<<<625 + 313, 256, 0, stream>>>(
        esrc, etgt, etype, count, slots,
        hidden, time_emb, Wqs, Wks, Wvs, bq, Qb, KVb);
    attn_kernel<<<(B_ * N_) / 4, 256, 0, stream>>>(
        Qb, KVb, Kt, Vt, ebt, count, slots, aggb);
    mlp_mfma_kernel<<<313, 256, 0, stream>>>(
        hidden, aggb, time_emb, W1s, W2s, b1, b2, gamma, beta, out);
}